// Round 2
// 187.542 us; speedup vs baseline: 1.2767x; 1.2767x over previous
//
#include <hip/hip_runtime.h>
#include <hip/hip_bf16.h>
#include <math.h>

#define NEG_SLOPE 0.2f
#define BSH    7          // log2(nodes per bucket)
#define BNODES 128        // nodes per bucket
#define CAP    4096       // max edges per bucket in LDS (mean 2048, sigma ~45)
#define MAXB   1024       // bucket count (covers up to 131072 nodes)
#define NCHUNK 512        // partition chunks
#define CEMAX  3200       // max edges per chunk staged in LDS (CE = 3125)

typedef __attribute__((ext_vector_type(8))) short bf16x8;
typedef __attribute__((ext_vector_type(4))) float f32x4;

__device__ __forceinline__ float leaky(float v) { return v >= 0.0f ? v : NEG_SLOPE * v; }
__device__ __forceinline__ int clampi(int v, int lo, int hi) {
    return v < lo ? lo : (v > hi ? hi : v);
}
// decode packed bf16 pair (low word / high word of a uint)
__device__ __forceinline__ float bflo(unsigned u) { return __uint_as_float(u << 16); }
__device__ __forceinline__ float bfhi(unsigned u) { return __uint_as_float(u & 0xFFFF0000u); }
// fp32 -> bf16 round-to-nearest-even
__device__ __forceinline__ unsigned short f2bf(float f) {
    unsigned u = __float_as_uint(f);
    return (unsigned short)((u + 0x7FFFu + ((u >> 16) & 1u)) >> 16);
}
__device__ __forceinline__ bf16x8 pack8(float4 a, float4 b) {
    bf16x8 r;
    r[0] = (short)f2bf(a.x); r[1] = (short)f2bf(a.y);
    r[2] = (short)f2bf(a.z); r[3] = (short)f2bf(a.w);
    r[4] = (short)f2bf(b.x); r[5] = (short)f2bf(b.y);
    r[6] = (short)f2bf(b.z); r[7] = (short)f2bf(b.w);
    return r;
}

// K1: h = x @ W via MFMA 16x16x32 bf16. Block 512 (8 waves), 128 nodes/block;
// wave = 16 nodes x 64 features. A-frags from global directly; W staged once
// per block into LDS in B-fragment order. Fused epilogue: a_s/a_d via quad
// shuffle reduce; h stored bf16.
__global__ __launch_bounds__(512) void k_linear(
    const float* __restrict__ x, const float* __restrict__ W,
    const float* __restrict__ att_src, const float* __restrict__ att_dst,
    __hip_bfloat16* __restrict__ h, float* __restrict__ a_s,
    float* __restrict__ a_d, int N)
{
    __shared__ short wlds[16 * 64 * 8];   // 16 frag-sets x 64 lanes x 8 bf16 = 16 KB

    const int tid = threadIdx.x;
    for (int idx = tid; idx < 1024; idx += 512) {
        int f = idx >> 6, L = idx & 63;
        int t = f >> 2, k0i = f & 3;
        int kbase = k0i * 32 + (L >> 4) * 8;
        int c = t * 16 + (L & 15);
        unsigned short v[8];
#pragma unroll
        for (int j = 0; j < 8; ++j) v[j] = f2bf(W[(kbase + j) * 64 + c]);
        uint4 p;
        p.x = (unsigned)v[0] | ((unsigned)v[1] << 16);
        p.y = (unsigned)v[2] | ((unsigned)v[3] << 16);
        p.z = (unsigned)v[4] | ((unsigned)v[5] << 16);
        p.w = (unsigned)v[6] | ((unsigned)v[7] << 16);
        ((uint4*)wlds)[idx] = p;
    }
    __syncthreads();

    const int lane = tid & 63;
    const int w    = tid >> 6;
    const int base = blockIdx.x * 128 + w * 16;
    const int m    = lane & 15;
    const int quad = lane >> 4;

    int rowc = min(base + m, N - 1);
    const float4* xr = (const float4*)x + (size_t)rowc * 32;

    bf16x8 afrag[4];
#pragma unroll
    for (int k0i = 0; k0i < 4; ++k0i) {
        float4 f0 = xr[k0i * 8 + quad * 2 + 0];
        float4 f1 = xr[k0i * 8 + quad * 2 + 1];
        afrag[k0i] = pack8(f0, f1);
    }

    f32x4 acc[4];
#pragma unroll
    for (int t = 0; t < 4; ++t) acc[t] = (f32x4){0.f, 0.f, 0.f, 0.f};

    const bf16x8* wf = (const bf16x8*)wlds;
#pragma unroll
    for (int t = 0; t < 4; ++t) {
#pragma unroll
        for (int k0i = 0; k0i < 4; ++k0i) {
            bf16x8 b = wf[(t * 4 + k0i) * 64 + lane];
            acc[t] = __builtin_amdgcn_mfma_f32_16x16x32_bf16(afrag[k0i], b, acc[t], 0, 0, 0);
        }
    }

    float ps[4] = {0.f, 0.f, 0.f, 0.f};
    float pd[4] = {0.f, 0.f, 0.f, 0.f};
#pragma unroll
    for (int t = 0; t < 4; ++t) {
        float as_c = att_src[t * 16 + m];
        float ad_c = att_dst[t * 16 + m];
#pragma unroll
        for (int q = 0; q < 4; ++q) {
            ps[q] = fmaf(acc[t][q], as_c, ps[q]);
            pd[q] = fmaf(acc[t][q], ad_c, pd[q]);
        }
    }
#pragma unroll
    for (int t = 0; t < 4; ++t) {
#pragma unroll
        for (int q = 0; q < 4; ++q) {
            int n = base + quad * 4 + q;
            if (n < N) h[(size_t)n * 64 + t * 16 + m] = __float2bfloat16(acc[t][q]);
        }
    }
#pragma unroll
    for (int q = 0; q < 4; ++q) {
        ps[q] += __shfl_xor(ps[q], 1, 64);
        ps[q] += __shfl_xor(ps[q], 2, 64);
        ps[q] += __shfl_xor(ps[q], 4, 64);
        ps[q] += __shfl_xor(ps[q], 8, 64);
        pd[q] += __shfl_xor(pd[q], 1, 64);
        pd[q] += __shfl_xor(pd[q], 2, 64);
        pd[q] += __shfl_xor(pd[q], 4, 64);
        pd[q] += __shfl_xor(pd[q], 8, 64);
    }
    if (m == 0) {
#pragma unroll
        for (int q = 0; q < 4; ++q) {
            int n = base + quad * 4 + q;
            if (n < N) { a_s[n] = ps[q]; a_d[n] = pd[q]; }
        }
    }
}

// K2: single-pass chunk-local binning (replaces k_chist + k_scan_a + k_scan_b
// + k_part). Block c owns edges [c*CE, c*CE+ne): LDS histogram over 1024
// buckets, LDS scan, LDS scatter into a staging buffer, then FULLY COALESCED
// global writes: binned[c*CE ..] (chunk-major, bucket-sorted within chunk)
// and offc[c*(MAXB+1) ..] (per-chunk exclusive bucket offsets + total).
// No global scan, no global scatter -> no cross-XCD RMW write amplification.
__global__ __launch_bounds__(512) void k_part2(
    const int* __restrict__ ei, unsigned* __restrict__ binned,
    int* __restrict__ offc, int E, int N, int CE)
{
    __shared__ int hist[MAXB];
    __shared__ int off[MAXB];
    __shared__ int cur[MAXB];
    __shared__ int s[512];
    __shared__ unsigned stage[CEMAX];

    const int c   = blockIdx.x;
    const int tid = threadIdx.x;
    const int e0  = c * CE;
    const int e1  = min(E, e0 + CE);
    const int ne  = e1 - e0;

    for (int i = tid; i < MAXB; i += 512) hist[i] = 0;
    __syncthreads();
    for (int e = e0 + tid; e < e1; e += 512) {
        int dst = clampi(ei[E + e], 0, N - 1);
        atomicAdd(&hist[dst >> BSH], 1);
    }
    __syncthreads();
    // exclusive scan of hist[1024] with 512 threads (pair-sum Hillis-Steele)
    int a0 = hist[2 * tid], a1 = hist[2 * tid + 1];
    int psum = a0 + a1;
    s[tid] = psum;
    __syncthreads();
    for (int d = 1; d < 512; d <<= 1) {
        int v = (tid >= d) ? s[tid - d] : 0;
        __syncthreads();
        s[tid] += v;
        __syncthreads();
    }
    int excl = s[tid] - psum;
    off[2 * tid]     = excl;
    off[2 * tid + 1] = excl + a0;
    cur[2 * tid]     = excl;
    cur[2 * tid + 1] = excl + a0;
    __syncthreads();
    for (int e = e0 + tid; e < e1; e += 512) {
        int src = clampi(ei[e],     0, N - 1);
        int dst = clampi(ei[E + e], 0, N - 1);
        int pos = atomicAdd(&cur[dst >> BSH], 1);
        stage[clampi(pos, 0, CEMAX - 1)] =
            ((unsigned)(dst & (BNODES - 1)) << 17) | (unsigned)src;
    }
    __syncthreads();
    for (int i = tid; i < ne; i += 512) binned[e0 + i] = stage[i];
    int* oc = offc + (size_t)c * (MAXB + 1);
    for (int i = tid; i < MAXB; i += 512) oc[i] = off[i];
    if (tid == 0) oc[MAXB] = ne;
}

// K3: one block (512 threads, 8 waves) per 128-node bucket.
// Phase 0: gather this bucket's edge runs from all 512 chunks (thread c = run
//   of chunk c, ~3 edges), build node CSR, and — fused, edge-parallel —
//   compute w = exp(leaky(a_s[src]+a_d[dst])) per edge into LDS uint2(src,w);
//   denominators l[] via LDS atomics. Self-loop terms precomputed per node.
// Phase B: lane = (node-slot p = lane>>3, octet q = lane&7). Each lane owns
//   8 features of one node -> NO cross-lane ops in the hot loop (was ~32
//   shuffles/node). Per edge: ds_read_b64 (src,w) + 16B gather + 8 fma,
//   depth-1 software pipeline; 8 nodes per wave, 2 passes.
__global__ __launch_bounds__(512) void k_agg(
    const unsigned* __restrict__ binned, const int* __restrict__ offc,
    const float* __restrict__ a_s, const float* __restrict__ a_d,
    const __hip_bfloat16* __restrict__ hm, const float* __restrict__ bias,
    float* __restrict__ out, int N, int CE)
{
    __shared__ int   cnt[BNODES];
    __shared__ int   st[BNODES];
    __shared__ int   cur[BNODES];
    __shared__ float lsum[BNODES];
    __shared__ float wsl[BNODES];
    __shared__ float adl[BNODES];
    __shared__ uint2 ew[CAP];          // .x = src node, .y = f32 bits of w

    const int tid   = threadIdx.x;
    const int b     = blockIdx.x;
    const int nbase = b << BSH;

    if (tid < BNODES) {
        cnt[tid] = 0;
        int n = nbase + tid;
        float as = 0.f, ad = 0.f;
        if (n < N) { as = a_s[n]; ad = a_d[n]; }
        adl[tid] = ad;
        float v = (n < N) ? __expf(leaky(as + ad)) : 0.f;
        wsl[tid]  = v;                 // self-loop weight
        lsum[tid] = v;                 // denominator starts with self loop
    }
    // this bucket's run inside chunk `tid`
    int rbase = 0, rcnt = 0;
    if (tid < NCHUNK) {
        const int* oc = offc + (size_t)tid * (MAXB + 1);
        int o0 = clampi(oc[b],     0, CE);
        int o1 = clampi(oc[b + 1], o0, CE);
        rbase = tid * CE + o0;
        rcnt  = o1 - o0;
    }
    __syncthreads();
    // pass 1: per-node histogram
    for (int i = 0; i < rcnt; ++i) {
        unsigned pk = binned[rbase + i];
        atomicAdd(&cnt[(pk >> 17) & (BNODES - 1)], 1);
    }
    __syncthreads();
    if (tid < BNODES) st[tid] = cnt[tid];
    __syncthreads();
    for (int d = 1; d < BNODES; d <<= 1) {      // Hillis-Steele inclusive
        int v = (tid < BNODES && tid >= d) ? st[tid - d] : 0;
        __syncthreads();
        if (tid < BNODES) st[tid] += v;
        __syncthreads();
    }
    if (tid < BNODES) { st[tid] -= cnt[tid]; cur[tid] = st[tid]; }  // exclusive
    __syncthreads();
    // pass 2: scatter + fused attention weight + denominator
    for (int i = 0; i < rcnt; ++i) {
        unsigned pk = binned[rbase + i];
        int ld  = (int)(pk >> 17) & (BNODES - 1);
        int src = (int)(pk & 0x1FFFFu);
        float wv = __expf(leaky(a_s[src] + adl[ld]));
        int pos = atomicAdd(&cur[ld], 1);
        if (pos < CAP) ew[pos] = make_uint2((unsigned)src, __float_as_uint(wv));
        atomicAdd(&lsum[ld], wv);
    }
    __syncthreads();

    // Phase B
    const int lane = tid & 63;
    const int w    = tid >> 6;       // wave 0..7
    const int q    = lane & 7;       // feature octet: features 8q..8q+7
    const int p    = lane >> 3;      // node slot 0..7
    const uint4*  h4 = (const uint4*)hm;
    const float4* b4 = (const float4*)bias;
    const float4 bb0 = b4[2 * q];
    const float4 bb1 = b4[2 * q + 1];

#pragma unroll 1
    for (int t = 0; t < 2; ++t) {
        int ln = t * 64 + w * 8 + p;
        int n  = nbase + ln;
        if (n >= N) continue;
        int deg = cnt[ln];
        int s0  = st[ln];
        if (s0 > CAP) s0 = CAP;            // defensive (never in practice)
        if (deg > CAP - s0) deg = CAP - s0;

        // self-loop contribution (each lane owns its octet exactly once)
        float wself = wsl[ln];
        uint4 U = h4[(size_t)n * 8 + q];
        float acc0 = wself * bflo(U.x), acc1 = wself * bfhi(U.x);
        float acc2 = wself * bflo(U.y), acc3 = wself * bfhi(U.y);
        float acc4 = wself * bflo(U.z), acc5 = wself * bfhi(U.z);
        float acc6 = wself * bflo(U.w), acc7 = wself * bfhi(U.w);

        float wc = 0.f;
        if (deg > 0) {
            uint2 e0 = ew[s0];
            wc = __uint_as_float(e0.y);
            U  = h4[(size_t)e0.x * 8 + q];
        }
        for (int j = 0; j < deg; ++j) {
            uint4 U2 = make_uint4(0u, 0u, 0u, 0u);
            float w2 = 0.f;
            if (j + 1 < deg) {             // prefetch next edge (depth-1)
                uint2 e1 = ew[s0 + j + 1];
                w2 = __uint_as_float(e1.y);
                U2 = h4[(size_t)e1.x * 8 + q];
            }
            acc0 = fmaf(wc, bflo(U.x), acc0);
            acc1 = fmaf(wc, bfhi(U.x), acc1);
            acc2 = fmaf(wc, bflo(U.y), acc2);
            acc3 = fmaf(wc, bfhi(U.y), acc3);
            acc4 = fmaf(wc, bflo(U.z), acc4);
            acc5 = fmaf(wc, bfhi(U.z), acc5);
            acc6 = fmaf(wc, bflo(U.w), acc6);
            acc7 = fmaf(wc, bfhi(U.w), acc7);
            U = U2; wc = w2;
        }

        float inv = 1.0f / lsum[ln];
        float4 o0, o1;
        o0.x = bb0.x + acc0 * inv;
        o0.y = bb0.y + acc1 * inv;
        o0.z = bb0.z + acc2 * inv;
        o0.w = bb0.w + acc3 * inv;
        o1.x = bb1.x + acc4 * inv;
        o1.y = bb1.y + acc5 * inv;
        o1.z = bb1.z + acc6 * inv;
        o1.w = bb1.w + acc7 * inv;
        float4* o4 = (float4*)out;
        o4[(size_t)n * 16 + 2 * q + 0] = o0;
        o4[(size_t)n * 16 + 2 * q + 1] = o1;
    }
}

extern "C" void kernel_launch(void* const* d_in, const int* in_sizes, int n_in,
                              void* d_out, int out_size, void* d_ws, size_t ws_size,
                              hipStream_t stream)
{
    const float* x       = (const float*)d_in[0];
    const int*   ei      = (const int*)d_in[1];      // int32 per harness contract
    const float* W       = (const float*)d_in[2];
    const float* att_src = (const float*)d_in[3];
    const float* att_dst = (const float*)d_in[4];
    const float* bias    = (const float*)d_in[5];
    float*       out     = (float*)d_out;

    const int N = in_sizes[0] / 128;   // 100000
    const int E = in_sizes[1] / 2;     // 1600000

    // ws (~22 MB): h_bf16[N*64] | a_s[N] | a_d[N] |
    //              offc[NCHUNK*(MAXB+1)] | binned uint[E]
    __hip_bfloat16* h      = (__hip_bfloat16*)d_ws;
    float*          a_s    = (float*)(h + (size_t)N * 64);
    float*          a_d    = a_s + N;
    int*            offc   = (int*)(a_d + N);                 // 524800 ints
    unsigned*       binned = (unsigned*)(offc + NCHUNK * (MAXB + 1));

    const int CE = (E + NCHUNK - 1) / NCHUNK;   // 3125 edges per chunk (<= CEMAX)
    const int NB = (N + BNODES - 1) >> BSH;     // 782 agg buckets

    int nb_lin = (N + 127) / 128;               // 782 blocks (128 nodes each)

    k_linear<<<nb_lin, 512, 0, stream>>>(x, W, att_src, att_dst, h, a_s, a_d, N);
    k_part2 <<<NCHUNK, 512, 0, stream>>>(ei, binned, offc, E, N, CE);
    k_agg   <<<NB,     512, 0, stream>>>(binned, offc, a_s, a_d, h, bias, out, N, CE);
}

// Round 3
// 168.796 us; speedup vs baseline: 1.4185x; 1.1111x over previous
//
#include <hip/hip_runtime.h>
#include <hip/hip_bf16.h>
#include <math.h>

#define NEG_SLOPE 0.2f
#define BSH    7          // log2(nodes per bucket)
#define BNODES 128        // nodes per bucket
#define CAP    2560       // max edges per bucket in LDS (mean 2048, sigma ~45 -> 11 sigma)
#define MAXB   1024       // bucket count (covers up to 131072 nodes)
#define NCHUNK 256        // partition chunks
#define CEMAX  6272       // max edges per chunk staged in LDS (CE = 6250)
#define SMEMB  39424      // fused-kernel LDS bytes: part path 39424 > linear 16384

typedef __attribute__((ext_vector_type(8))) short bf16x8;
typedef __attribute__((ext_vector_type(4))) float f32x4;

__device__ __forceinline__ float leaky(float v) { return v >= 0.0f ? v : NEG_SLOPE * v; }
__device__ __forceinline__ int clampi(int v, int lo, int hi) {
    return v < lo ? lo : (v > hi ? hi : v);
}
// decode packed bf16 pair (low word / high word of a uint)
__device__ __forceinline__ float bflo(unsigned u) { return __uint_as_float(u << 16); }
__device__ __forceinline__ float bfhi(unsigned u) { return __uint_as_float(u & 0xFFFF0000u); }
// fp32 -> bf16 round-to-nearest-even
__device__ __forceinline__ unsigned short f2bf(float f) {
    unsigned u = __float_as_uint(f);
    return (unsigned short)((u + 0x7FFFu + ((u >> 16) & 1u)) >> 16);
}
__device__ __forceinline__ bf16x8 pack8(float4 a, float4 b) {
    bf16x8 r;
    r[0] = (short)f2bf(a.x); r[1] = (short)f2bf(a.y);
    r[2] = (short)f2bf(a.z); r[3] = (short)f2bf(a.w);
    r[4] = (short)f2bf(b.x); r[5] = (short)f2bf(b.y);
    r[6] = (short)f2bf(b.z); r[7] = (short)f2bf(b.w);
    return r;
}

// K1 (fused): blocks [0, nb_lin) run the MFMA linear+epilogue; blocks
// [nb_lin, nb_lin+NCHUNK) run the chunk-local edge binning. The two halves
// are data-independent -> they execute CONCURRENTLY instead of serializing
// as two launches. LDS is a union (39.4 KB), which changes no occupancy cap.
__global__ __launch_bounds__(512) void k_fused(
    const float* __restrict__ x, const float* __restrict__ W,
    const float* __restrict__ att_src, const float* __restrict__ att_dst,
    __hip_bfloat16* __restrict__ h, float* __restrict__ a_s,
    float* __restrict__ a_d, const int* __restrict__ ei,
    unsigned* __restrict__ binned, int* __restrict__ offc,
    int N, int E, int CE, int nb_lin)
{
    __shared__ int4 smem4[SMEMB / 16];
    const int tid = threadIdx.x;

    if ((int)blockIdx.x < nb_lin) {
        // ---- linear path: h = x @ W via MFMA 16x16x32 bf16 ----
        short* wlds = (short*)smem4;      // 16 frag-sets x 64 lanes x 8 bf16 = 16 KB

        for (int idx = tid; idx < 1024; idx += 512) {
            int f = idx >> 6, L = idx & 63;
            int t = f >> 2, k0i = f & 3;
            int kbase = k0i * 32 + (L >> 4) * 8;
            int c = t * 16 + (L & 15);
            unsigned short v[8];
#pragma unroll
            for (int j = 0; j < 8; ++j) v[j] = f2bf(W[(kbase + j) * 64 + c]);
            uint4 p;
            p.x = (unsigned)v[0] | ((unsigned)v[1] << 16);
            p.y = (unsigned)v[2] | ((unsigned)v[3] << 16);
            p.z = (unsigned)v[4] | ((unsigned)v[5] << 16);
            p.w = (unsigned)v[6] | ((unsigned)v[7] << 16);
            ((uint4*)wlds)[idx] = p;
        }
        __syncthreads();

        const int lane = tid & 63;
        const int w    = tid >> 6;
        const int base = blockIdx.x * 128 + w * 16;
        const int m    = lane & 15;
        const int quad = lane >> 4;

        int rowc = min(base + m, N - 1);
        const float4* xr = (const float4*)x + (size_t)rowc * 32;

        bf16x8 afrag[4];
#pragma unroll
        for (int k0i = 0; k0i < 4; ++k0i) {
            float4 f0 = xr[k0i * 8 + quad * 2 + 0];
            float4 f1 = xr[k0i * 8 + quad * 2 + 1];
            afrag[k0i] = pack8(f0, f1);
        }

        f32x4 acc[4];
#pragma unroll
        for (int t = 0; t < 4; ++t) acc[t] = (f32x4){0.f, 0.f, 0.f, 0.f};

        const bf16x8* wf = (const bf16x8*)wlds;
#pragma unroll
        for (int t = 0; t < 4; ++t) {
#pragma unroll
            for (int k0i = 0; k0i < 4; ++k0i) {
                bf16x8 bfr = wf[(t * 4 + k0i) * 64 + lane];
                acc[t] = __builtin_amdgcn_mfma_f32_16x16x32_bf16(afrag[k0i], bfr, acc[t], 0, 0, 0);
            }
        }

        float ps[4] = {0.f, 0.f, 0.f, 0.f};
        float pd[4] = {0.f, 0.f, 0.f, 0.f};
#pragma unroll
        for (int t = 0; t < 4; ++t) {
            float as_c = att_src[t * 16 + m];
            float ad_c = att_dst[t * 16 + m];
#pragma unroll
            for (int q = 0; q < 4; ++q) {
                ps[q] = fmaf(acc[t][q], as_c, ps[q]);
                pd[q] = fmaf(acc[t][q], ad_c, pd[q]);
            }
        }
#pragma unroll
        for (int t = 0; t < 4; ++t) {
#pragma unroll
            for (int q = 0; q < 4; ++q) {
                int n = base + quad * 4 + q;
                if (n < N) h[(size_t)n * 64 + t * 16 + m] = __float2bfloat16(acc[t][q]);
            }
        }
#pragma unroll
        for (int q = 0; q < 4; ++q) {
            ps[q] += __shfl_xor(ps[q], 1, 64);
            ps[q] += __shfl_xor(ps[q], 2, 64);
            ps[q] += __shfl_xor(ps[q], 4, 64);
            ps[q] += __shfl_xor(ps[q], 8, 64);
            pd[q] += __shfl_xor(pd[q], 1, 64);
            pd[q] += __shfl_xor(pd[q], 2, 64);
            pd[q] += __shfl_xor(pd[q], 4, 64);
            pd[q] += __shfl_xor(pd[q], 8, 64);
        }
        if (m == 0) {
#pragma unroll
            for (int q = 0; q < 4; ++q) {
                int n = base + quad * 4 + q;
                if (n < N) { a_s[n] = ps[q]; a_d[n] = pd[q]; }
            }
        }
    } else {
        // ---- partition path: chunk-local binning ----
        int* hist = (int*)smem4;              // 1024
        int* off  = hist + MAXB;              // 1024
        int* cur  = off + MAXB;               // 1024
        int* s    = cur + MAXB;               // 512
        unsigned* stage = (unsigned*)(s + 512);  // CEMAX = 6272

        const int c  = (int)blockIdx.x - nb_lin;
        const int e0 = c * CE;
        const int e1 = min(E, e0 + CE);
        const int ne = e1 - e0;

        for (int i = tid; i < MAXB; i += 512) hist[i] = 0;
        __syncthreads();
        for (int e = e0 + tid; e < e1; e += 512) {
            int dst = clampi(ei[E + e], 0, N - 1);
            atomicAdd(&hist[dst >> BSH], 1);
        }
        __syncthreads();
        // exclusive scan of hist[1024] with 512 threads (pair-sum Hillis-Steele)
        int a0 = hist[2 * tid], a1 = hist[2 * tid + 1];
        int psum = a0 + a1;
        s[tid] = psum;
        __syncthreads();
        for (int d = 1; d < 512; d <<= 1) {
            int v = (tid >= d) ? s[tid - d] : 0;
            __syncthreads();
            s[tid] += v;
            __syncthreads();
        }
        int excl = s[tid] - psum;
        off[2 * tid]     = excl;
        off[2 * tid + 1] = excl + a0;
        cur[2 * tid]     = excl;
        cur[2 * tid + 1] = excl + a0;
        __syncthreads();
        for (int e = e0 + tid; e < e1; e += 512) {
            int src = clampi(ei[e],     0, N - 1);
            int dst = clampi(ei[E + e], 0, N - 1);
            int pos = atomicAdd(&cur[dst >> BSH], 1);
            stage[clampi(pos, 0, CEMAX - 1)] =
                ((unsigned)(dst & (BNODES - 1)) << 17) | (unsigned)src;
        }
        __syncthreads();
        for (int i = tid; i < ne; i += 512) binned[e0 + i] = stage[i];
        int* oc = offc + (size_t)c * (MAXB + 1);
        for (int i = tid; i < MAXB; i += 512) oc[i] = off[i];
        if (tid == 0) oc[MAXB] = ne;
    }
}

// K2: one block (512 threads, 8 waves) per 128-node bucket.
// Phase 0 (v3): scan the 256 per-chunk run lengths in LDS; element-parallel
//   COALESCED copy of the bucket's edges into eraw[] (one read of binned,
//   consecutive threads -> consecutive addresses via 8-step binary search);
//   then node histogram + scan + weighted scatter entirely from LDS.
// Phase B: lane = (node-slot p = lane>>3, octet q = lane&7); each lane owns
//   8 features of one node -> no cross-lane ops. Per edge: ds_read_b64
//   (src,w) + 16B gather + 8 fma, depth-1 software pipeline.
__global__ __launch_bounds__(512) void k_agg(
    const unsigned* __restrict__ binned, const int* __restrict__ offc,
    const float* __restrict__ a_s, const float* __restrict__ a_d,
    const __hip_bfloat16* __restrict__ hm, const float* __restrict__ bias,
    float* __restrict__ out, int N, int CE)
{
    __shared__ int   cnt[BNODES];
    __shared__ int   st[BNODES];
    __shared__ int   cur[BNODES];
    __shared__ float lsum[BNODES];
    __shared__ float wsl[BNODES];
    __shared__ float adl[BNODES];
    __shared__ int   runScan[NCHUNK + 1];
    __shared__ int   gbase[NCHUNK];
    __shared__ int   sc[NCHUNK];
    __shared__ unsigned eraw[CAP];
    __shared__ uint2 ew[CAP];          // .x = src node, .y = f32 bits of w

    const int tid   = threadIdx.x;
    const int b     = blockIdx.x;
    const int nbase = b << BSH;

    if (tid < BNODES) {
        cnt[tid] = 0;
        int n = nbase + tid;
        float as = 0.f, ad = 0.f;
        if (n < N) { as = a_s[n]; ad = a_d[n]; }
        adl[tid] = ad;
        float v = (n < N) ? __expf(leaky(as + ad)) : 0.f;
        wsl[tid]  = v;                 // self-loop weight
        lsum[tid] = v;                 // denominator starts with self loop
    }
    int rc = 0;
    if (tid < NCHUNK) {
        const int* oc = offc + (size_t)tid * (MAXB + 1);
        int o0 = clampi(oc[b],     0, CE);
        int o1 = clampi(oc[b + 1], o0, CE);
        rc = o1 - o0;
        gbase[tid] = tid * CE + o0;
        sc[tid] = rc;
    }
    __syncthreads();
    for (int d = 1; d < NCHUNK; d <<= 1) {      // inclusive scan of run lengths
        int v = (tid < NCHUNK && tid >= d) ? sc[tid - d] : 0;
        __syncthreads();
        if (tid < NCHUNK) sc[tid] += v;
        __syncthreads();
    }
    if (tid < NCHUNK) runScan[tid] = sc[tid] - rc;   // exclusive
    if (tid == NCHUNK - 1) runScan[NCHUNK] = sc[NCHUNK - 1];
    __syncthreads();
    int n_e = runScan[NCHUNK];
    if (n_e > CAP) n_e = CAP;          // statistically never

    // coalesced element-parallel copy: global binned -> LDS eraw
    for (int i = tid; i < n_e; i += 512) {
        int c = 0;
#pragma unroll
        for (int stp = NCHUNK >> 1; stp >= 1; stp >>= 1)
            if (runScan[c + stp] <= i) c += stp;
        eraw[i] = binned[(size_t)gbase[c] + (i - runScan[c])];
    }
    __syncthreads();
    // per-node histogram (LDS only)
    for (int i = tid; i < n_e; i += 512)
        atomicAdd(&cnt[(eraw[i] >> 17) & (BNODES - 1)], 1);
    __syncthreads();
    if (tid < BNODES) st[tid] = cnt[tid];
    __syncthreads();
    for (int d = 1; d < BNODES; d <<= 1) {      // Hillis-Steele inclusive
        int v = (tid < BNODES && tid >= d) ? st[tid - d] : 0;
        __syncthreads();
        if (tid < BNODES) st[tid] += v;
        __syncthreads();
    }
    if (tid < BNODES) { st[tid] -= cnt[tid]; cur[tid] = st[tid]; }  // exclusive
    __syncthreads();
    // scatter + fused attention weight + denominator (LDS -> LDS)
    for (int i = tid; i < n_e; i += 512) {
        unsigned pk = eraw[i];
        int ld  = (int)(pk >> 17) & (BNODES - 1);
        int src = (int)(pk & 0x1FFFFu);
        float wv = __expf(leaky(a_s[src] + adl[ld]));
        int pos = atomicAdd(&cur[ld], 1);
        if (pos < CAP) ew[pos] = make_uint2((unsigned)src, __float_as_uint(wv));
        atomicAdd(&lsum[ld], wv);
    }
    __syncthreads();

    // Phase B
    const int lane = tid & 63;
    const int w    = tid >> 6;       // wave 0..7
    const int q    = lane & 7;       // feature octet: features 8q..8q+7
    const int p    = lane >> 3;      // node slot 0..7
    const uint4*  h4 = (const uint4*)hm;
    const float4* b4 = (const float4*)bias;
    const float4 bb0 = b4[2 * q];
    const float4 bb1 = b4[2 * q + 1];

#pragma unroll 1
    for (int t = 0; t < 2; ++t) {
        int ln = t * 64 + w * 8 + p;
        int n  = nbase + ln;
        if (n >= N) continue;
        int deg = cnt[ln];
        int s0  = st[ln];
        if (s0 > CAP) s0 = CAP;            // defensive (never in practice)
        if (deg > CAP - s0) deg = CAP - s0;

        // self-loop contribution (each lane owns its octet exactly once)
        float wself = wsl[ln];
        uint4 U = h4[(size_t)n * 8 + q];
        float acc0 = wself * bflo(U.x), acc1 = wself * bfhi(U.x);
        float acc2 = wself * bflo(U.y), acc3 = wself * bfhi(U.y);
        float acc4 = wself * bflo(U.z), acc5 = wself * bfhi(U.z);
        float acc6 = wself * bflo(U.w), acc7 = wself * bfhi(U.w);

        float wc = 0.f;
        if (deg > 0) {
            uint2 e0 = ew[s0];
            wc = __uint_as_float(e0.y);
            U  = h4[(size_t)e0.x * 8 + q];
        }
        for (int j = 0; j < deg; ++j) {
            uint4 U2 = make_uint4(0u, 0u, 0u, 0u);
            float w2 = 0.f;
            if (j + 1 < deg) {             // prefetch next edge (depth-1)
                uint2 e1 = ew[s0 + j + 1];
                w2 = __uint_as_float(e1.y);
                U2 = h4[(size_t)e1.x * 8 + q];
            }
            acc0 = fmaf(wc, bflo(U.x), acc0);
            acc1 = fmaf(wc, bfhi(U.x), acc1);
            acc2 = fmaf(wc, bflo(U.y), acc2);
            acc3 = fmaf(wc, bfhi(U.y), acc3);
            acc4 = fmaf(wc, bflo(U.z), acc4);
            acc5 = fmaf(wc, bfhi(U.z), acc5);
            acc6 = fmaf(wc, bflo(U.w), acc6);
            acc7 = fmaf(wc, bfhi(U.w), acc7);
            U = U2; wc = w2;
        }

        float inv = 1.0f / lsum[ln];
        float4 o0, o1;
        o0.x = bb0.x + acc0 * inv;
        o0.y = bb0.y + acc1 * inv;
        o0.z = bb0.z + acc2 * inv;
        o0.w = bb0.w + acc3 * inv;
        o1.x = bb1.x + acc4 * inv;
        o1.y = bb1.y + acc5 * inv;
        o1.z = bb1.z + acc6 * inv;
        o1.w = bb1.w + acc7 * inv;
        float4* o4 = (float4*)out;
        o4[(size_t)n * 16 + 2 * q + 0] = o0;
        o4[(size_t)n * 16 + 2 * q + 1] = o1;
    }
}

extern "C" void kernel_launch(void* const* d_in, const int* in_sizes, int n_in,
                              void* d_out, int out_size, void* d_ws, size_t ws_size,
                              hipStream_t stream)
{
    const float* x       = (const float*)d_in[0];
    const int*   ei      = (const int*)d_in[1];      // int32 per harness contract
    const float* W       = (const float*)d_in[2];
    const float* att_src = (const float*)d_in[3];
    const float* att_dst = (const float*)d_in[4];
    const float* bias    = (const float*)d_in[5];
    float*       out     = (float*)d_out;

    const int N = in_sizes[0] / 128;   // 100000
    const int E = in_sizes[1] / 2;     // 1600000

    // ws (~21 MB): h_bf16[N*64] | a_s[N] | a_d[N] |
    //              offc[NCHUNK*(MAXB+1)] | binned uint[E]
    __hip_bfloat16* h      = (__hip_bfloat16*)d_ws;
    float*          a_s    = (float*)(h + (size_t)N * 64);
    float*          a_d    = a_s + N;
    int*            offc   = (int*)(a_d + N);                 // 262400 ints
    unsigned*       binned = (unsigned*)(offc + NCHUNK * (MAXB + 1));

    const int CE = (E + NCHUNK - 1) / NCHUNK;   // 6250 edges per chunk (<= CEMAX)
    const int NB = (N + BNODES - 1) >> BSH;     // 782 agg buckets
    const int nb_lin = (N + 127) / 128;         // 782 linear blocks

    k_fused<<<nb_lin + NCHUNK, 512, 0, stream>>>(x, W, att_src, att_dst,
                                                 h, a_s, a_d, ei, binned, offc,
                                                 N, E, CE, nb_lin);
    k_agg  <<<NB,              512, 0, stream>>>(binned, offc, a_s, a_d, h,
                                                 bias, out, N, CE);
}